// Round 5
// baseline (145.768 us; speedup 1.0000x reference)
//
#include <hip/hip_runtime.h>

#define NNODES 100000
#define NEDGES 3200000
#define CH     128
#define KPOOL  50000
#define NBUCK  (1 << 17)          // value buckets for f64 ranking
#define BUCK_SCALE 8192.0         // NBUCK / 16 (range [-8, 8))

// output offsets (floats)
#define OFF_X   0
#define OFF_EI  6400000
#define OFF_EA  12800000
#define OFF_REG 16000000
#define OFF_BAT 16050000
#define OFF_SC  16100000
#define OFF_NE  16200000

#define NB_EDGE   3125            // NEDGES / 1024
#define SCORE_BLK 25000           // blocks doing scores in k_scores_fill
#define FILL_BLK  2344            // blocks doing edge-out prefill (2.4M float4 / 1024)
#define POOL_BLK  12500           // pool blocks in k_poolesc

// ws layout (bytes)
#define WS_SCORE   0              // 800,000
#define WS_HIST    800000         // 524,288  (zero region start)
#define WS_KB      1324288        //  12,544
#define WS_SSTATE  1336832        //   1,024  (128 x u64 scan lookback)
#define WS_ESTATE  1337856        //  25,000  (3125 x u64 edge lookback)
#define WS_TICKETS 1362856        //       8  (zero region end)
#define WS_BBASE   1362864        // 524,288
#define WS_ELEMS   1887152        // 400,000
#define WS_PERM    2287152        // 400,000
#define ZERO_U4    35179          // (1362864 - 800000) / 16

#define AGGBIT (1ULL << 62)
#define INCBIT (1ULL << 63)

__device__ __forceinline__ int bucketOf(double s) {
    double u = (8.0 - s) * BUCK_SCALE;   // monotonic: score desc -> bucket asc
    int b = (int)u;
    if (b < 0) b = 0;
    if (b > NBUCK - 1) b = NBUCK - 1;
    return b;
}

// ticket-ordered decoupled lookback: returns exclusive prefix for `blk`
__device__ __forceinline__ unsigned lookback(unsigned long long* state, unsigned blk,
                                             unsigned total) {
    unsigned prefix = 0;
    if (blk == 0) {
        atomicExch(&state[0], INCBIT | (unsigned long long)total);
    } else {
        atomicExch(&state[blk], AGGBIT | (unsigned long long)total);
        int j = (int)blk - 1;
        for (;;) {
            unsigned long long v;
            do {
                v = atomicAdd(&state[j], 0ULL);
                if (!(v >> 62)) __builtin_amdgcn_s_sleep(4);
            } while (!(v >> 62));
            prefix += (unsigned)v;
            if (v & INCBIT) break;
            --j;
        }
        atomicExch(&state[blk], INCBIT | (unsigned long long)(prefix + total));
    }
    return prefix;
}

// Z: zero hist + kb + lookback states + tickets (contiguous)
__global__ void k_init(uint4* __restrict__ z) {
    int idx = blockIdx.x * 256 + threadIdx.x;
    if (idx < ZERO_U4) z[idx] = make_uint4(0u, 0u, 0u, 0u);
}

// K1: scores (f64 accumulate -- bit-identical order) + fused edge-out prefill
__global__ void k_scores_fill(const float* __restrict__ x, const float* __restrict__ W,
                              const float* __restrict__ bias, double* __restrict__ score_d,
                              float* __restrict__ out, unsigned* __restrict__ hist) {
    int bid = blockIdx.x, tid = threadIdx.x;
    if (bid < SCORE_BLK) {
        int row  = bid * 4 + (tid >> 6);
        int lane = tid & 63;
        int c = lane * 2;
        float2 xv = *(const float2*)(x + (size_t)row * CH + c);
        double acc = (double)xv.x * (double)W[c] + (double)xv.y * (double)W[c + 1];
        for (int off = 32; off > 0; off >>= 1) acc += __shfl_down(acc, off, 64);
        if (lane == 0) {
            double s = acc + (double)bias[0];
            score_d[row] = s;
            out[OFF_SC + row] = (float)s;
            atomicAdd(&hist[bucketOf(s)], 1u);
        }
    } else {
        // prefill edge_index(-1) and edge_attr(0): 2.4M float4 starting at OFF_EI
        int fb = bid - SCORE_BLK;
        float4* dst = (float4*)(out + OFF_EI);
        const float4 neg = make_float4(-1.f, -1.f, -1.f, -1.f);
        const float4 zer = make_float4(0.f, 0.f, 0.f, 0.f);
#pragma unroll
        for (int q = 0; q < 4; ++q) {
            int f = fb * 1024 + q * 256 + tid;
            if (f < 2400000) dst[f] = (f < 1600000) ? neg : zer;
        }
    }
}

// S: bucket-histogram exclusive scan, single kernel via lookback -> global bbase
__global__ void k_scan_lb(const unsigned* __restrict__ hist, unsigned* __restrict__ bbase,
                          unsigned long long* __restrict__ sstate, unsigned* __restrict__ tickets) {
    __shared__ unsigned stkt, sprefix;
    __shared__ unsigned sc[256];
    int t = threadIdx.x;
    if (t == 0) stkt = atomicAdd(&tickets[0], 1u);
    __syncthreads();
    unsigned blk = stkt;
    int i0 = (int)blk * 1024 + t * 4;
    uint4 h = *(const uint4*)(hist + i0);
    unsigned s = h.x + h.y + h.z + h.w;
    sc[t] = s; __syncthreads();
    for (int off = 1; off < 256; off <<= 1) {
        unsigned v = (t >= off) ? sc[t - off] : 0u;
        __syncthreads(); sc[t] += v; __syncthreads();
    }
    unsigned excl = sc[t] - s;
    unsigned tot  = sc[255];
    if (t == 0) sprefix = lookback(sstate, blk, tot);
    __syncthreads();
    unsigned base = sprefix + excl;
    uint4 o; o.x = base; o.y = o.x + h.x; o.z = o.y + h.y; o.w = o.z + h.z;
    *(uint4*)(bbase + i0) = o;
}

// C: scatter node ids; consumes bbase (global excl -> global excl + count)
__global__ void k_scatter(const double* __restrict__ score_d, unsigned* __restrict__ bbase,
                          unsigned* __restrict__ elems) {
    int i = blockIdx.x * 256 + threadIdx.x;
    if (i >= NNODES) return;
    int b = bucketOf(score_d[i]);
    unsigned slot = atomicAdd(&bbase[b], 1u);
    elems[slot] = i;
}

// R: exact rank (desc score, tie -> lower index); keep bit for r < KPOOL
// post-scatter: bbase[b] = global_excl + hist[b]  =>  st = bbase[b] - hist[b]
__global__ void k_rank(const double* __restrict__ score_d, const unsigned* __restrict__ bbase,
                       const unsigned* __restrict__ hist, const unsigned* __restrict__ elems,
                       unsigned* __restrict__ perm, unsigned* __restrict__ kb) {
    int i = blockIdx.x * 256 + threadIdx.x;
    if (i >= NNODES) return;
    double s = score_d[i];
    int b = bucketOf(s);
    unsigned c = hist[b];
    unsigned st = bbase[b] - c;
    unsigned r = st;
    if (c > 1) {
        for (unsigned m = 0; m < c; ++m) {
            unsigned j = elems[st + m];
            if (j == (unsigned)i) continue;
            double sj = score_d[j];
            if (sj > s || (sj == s && j < (unsigned)i)) r++;
        }
    }
    perm[r] = (unsigned)i;
    if (r < KPOOL) atomicOr(&kb[i >> 5], 1u << (i & 31));
}

// P+E: fused pool-gather and single-pass edge compaction (lookback)
__global__ void k_poolesc(const float* __restrict__ x, const int* __restrict__ region,
                          const int* __restrict__ batch, const unsigned* __restrict__ perm,
                          const int* __restrict__ ei, const float* __restrict__ attr,
                          const unsigned* __restrict__ kb, unsigned long long* __restrict__ estate,
                          unsigned* __restrict__ tickets, float* __restrict__ out) {
    int tid = threadIdx.x;
    if (blockIdx.x < POOL_BLK) {
        int r    = blockIdx.x * 4 + (tid >> 6);
        int lane = tid & 63;
        unsigned i = perm[r];
        float2 v = *(const float2*)(x + (size_t)i * CH + lane * 2);
        *(float2*)(out + OFF_X + (size_t)r * CH + lane * 2) = v;
        if (lane == 0) {
            out[OFF_REG + r] = (float)region[i];
            out[OFF_BAT + r] = (float)batch[i];
        }
        return;
    }
    __shared__ unsigned stkt, sbase;
    __shared__ unsigned sc[256];
    __shared__ float sA[1024], sB[1024], sT[1024];
    if (tid == 0) stkt = atomicAdd(&tickets[1], 1u);
    __syncthreads();
    unsigned blk = stkt;                       // virtual block id = data chunk
    size_t e0 = (size_t)blk * 1024 + (size_t)tid * 4;
    int4 a = *(const int4*)(ei + e0);
    int4 b = *(const int4*)(ei + NEDGES + e0);
    float4 at = *(const float4*)(attr + e0);
    unsigned m0 = (kb[a.x >> 5] >> (a.x & 31)) & (kb[b.x >> 5] >> (b.x & 31)) & 1u;
    unsigned m1 = (kb[a.y >> 5] >> (a.y & 31)) & (kb[b.y >> 5] >> (b.y & 31)) & 1u;
    unsigned m2 = (kb[a.z >> 5] >> (a.z & 31)) & (kb[b.z >> 5] >> (b.z & 31)) & 1u;
    unsigned m3 = (kb[a.w >> 5] >> (a.w & 31)) & (kb[b.w >> 5] >> (b.w & 31)) & 1u;
    unsigned cnt = m0 + m1 + m2 + m3;
    sc[tid] = cnt; __syncthreads();
    for (int off = 1; off < 256; off <<= 1) {
        unsigned w = (tid >= off) ? sc[tid - off] : 0u;
        __syncthreads(); sc[tid] += w; __syncthreads();
    }
    unsigned p = sc[tid] - cnt;
    unsigned cntAll = sc[255];
    if (tid == 0) {
        unsigned prefix = lookback(estate, blk, cntAll);
        sbase = prefix;
        if (blk == NB_EDGE - 1) out[OFF_NE] = (float)(prefix + cntAll);
    }
    if (m0) { sA[p] = (float)a.x; sB[p] = (float)b.x; sT[p] = at.x; p++; }
    if (m1) { sA[p] = (float)a.y; sB[p] = (float)b.y; sT[p] = at.y; p++; }
    if (m2) { sA[p] = (float)a.z; sB[p] = (float)b.z; sT[p] = at.z; p++; }
    if (m3) { sA[p] = (float)a.w; sB[p] = (float)b.w; sT[p] = at.w; p++; }
    __syncthreads();
    unsigned base = sbase;
    for (unsigned u = tid; u < cntAll; u += 256) {
        out[OFF_EI + base + u]          = sA[u];
        out[OFF_EI + NEDGES + base + u] = sB[u];
        out[OFF_EA + base + u]          = sT[u];
    }
    // tail [total, NEDGES) already prefilled with -1/-1/0 by k_scores_fill
}

extern "C" void kernel_launch(void* const* d_in, const int* in_sizes, int n_in,
                              void* d_out, int out_size, void* d_ws, size_t ws_size,
                              hipStream_t stream) {
    const float* x      = (const float*)d_in[0];
    const int*   ei     = (const int*)d_in[1];
    const float* attr   = (const float*)d_in[2];
    const int*   region = (const int*)d_in[3];
    const int*   batch  = (const int*)d_in[4];
    const float* W      = (const float*)d_in[5];
    const float* bias   = (const float*)d_in[6];
    float* out = (float*)d_out;

    char* ws = (char*)d_ws;
    double*             score_d = (double*)(ws + WS_SCORE);
    unsigned*           hist    = (unsigned*)(ws + WS_HIST);
    unsigned*           kb      = (unsigned*)(ws + WS_KB);
    unsigned long long* sstate  = (unsigned long long*)(ws + WS_SSTATE);
    unsigned long long* estate  = (unsigned long long*)(ws + WS_ESTATE);
    unsigned*           tickets = (unsigned*)(ws + WS_TICKETS);
    unsigned*           bbase   = (unsigned*)(ws + WS_BBASE);
    unsigned*           elems   = (unsigned*)(ws + WS_ELEMS);
    unsigned*           perm    = (unsigned*)(ws + WS_PERM);

    k_init       <<<(ZERO_U4 + 255) / 256, 256, 0, stream>>>((uint4*)(ws + WS_HIST));
    k_scores_fill<<<SCORE_BLK + FILL_BLK, 256, 0, stream>>>(x, W, bias, score_d, out, hist);
    k_scan_lb    <<<NBUCK / 1024, 256, 0, stream>>>(hist, bbase, sstate, tickets);
    k_scatter    <<<(NNODES + 255) / 256, 256, 0, stream>>>(score_d, bbase, elems);
    k_rank       <<<(NNODES + 255) / 256, 256, 0, stream>>>(score_d, bbase, hist, elems, perm, kb);
    k_poolesc    <<<POOL_BLK + NB_EDGE, 256, 0, stream>>>(x, region, batch, perm, ei, attr,
                                                          kb, estate, tickets, out);
}